// Round 2
// baseline (306.187 us; speedup 1.0000x reference)
//
#include <hip/hip_runtime.h>

#define H 512
#define W 512
#define TILE 64
#define NT 256
#define SW 104                // LDS row stride in halfs (52 dwords, 20 banks)
#define SROWS 90
#define TPD (W / TILE)        // 8 tiles per dim
#define NBANKS 16
#define BANK_STRIDE 16
#define KMAX 3                // max erode items/thread: ceil(516/256)=3
// Tile px (y,x) lives at LDS (13+y, 16+x) in half precision. Staging
// clamp-replicates true image borders; replication self-propagates through
// the erode chain (region shrinks 1 row/pass, matching contamination), so
// NO guard refresh is needed.
//
// SINGLE-buffer in-place erode (ping-pong 2x18.7KB limited us to 4
// blocks/CU): per pass: compute all outputs into registers (all LDS reads
// pre-barrier, incl. t0), barrier A, write back in place, barrier B, dilate
// reads the new level. Pass R reads rows [12-R,78+R] == exactly the rows
// written by pass R+1, so in-place is as fresh as ping-pong at every edge.
//
// COLUMN TRIM: pass R's output is only consumed on half-cols [16-R,79+R]
// (R-1 more erodes at +-1 col each, then dilate +-1). Group range
// glo=(16-R)>>3, ghi=(79+R)>>3 -> 12 groups for R>=9, 10 groups for R<=8.
// Validity induction (in-place, stale cols outside the written window):
// V(11)=[1,94], V(10)=[2,93], V(9)=[3,92], V(R<=8)=[16-R,79+R] exactly —
// contamination from stale cols advances 1 col/pass, staying exactly 1 col
// outside the consumed range; final dilate reads cols [15,80] = V(1). Rows
// written [13-R,76+R]; final dilate reads rows [12,77] = pass-1 rows.
// G is dispatched as a template constant so it/G stays a magic-multiply.

typedef _Float16 h8 __attribute__((ext_vector_type(8)));
typedef _Float16 h4 __attribute__((ext_vector_type(4)));

__device__ __forceinline__ float sigmf(float x) {
  return 1.0f / (1.0f + __expf(-x));
}
__device__ __forceinline__ float4 ld4(const float* p) { return *(const float4*)p; }

__device__ __forceinline__ h8 min3v(h8 a, h8 b, h8 c) {
  return __builtin_elementwise_min(__builtin_elementwise_min(a, b), c);
}
__device__ __forceinline__ h8 max3v(h8 a, h8 b, h8 c) {
  return __builtin_elementwise_max(__builtin_elementwise_max(a, b), c);
}
__device__ __forceinline__ h8 shl1(h8 v, _Float16 e) {
  h8 r = __builtin_shufflevector(v, v, 7, 0, 1, 2, 3, 4, 5, 6);
  r[0] = e;
  return r;
}
__device__ __forceinline__ h8 shr1(h8 v, _Float16 e) {
  h8 r = __builtin_shufflevector(v, v, 1, 2, 3, 4, 5, 6, 7, 0);
  r[7] = e;
  return r;
}
// b32 loads of half pairs (keeps ds_read2 mergeability), extract one half.
__device__ __forceinline__ _Float16 hi_half(const _Float16* p) {
  unsigned v = *(const unsigned*)p;
  unsigned short s = (unsigned short)(v >> 16);
  return __builtin_bit_cast(_Float16, s);
}
__device__ __forceinline__ _Float16 lo_half(const _Float16* p) {
  unsigned v = *(const unsigned*)p;
  return __builtin_bit_cast(_Float16, (unsigned short)v);
}
__device__ __forceinline__ _Float16 hmax3(_Float16 a, _Float16 b, _Float16 c) {
  _Float16 m = a > b ? a : b;
  return m > c ? m : c;
}

template <int G, int GLO>
__device__ __forceinline__ void erode_compute(const _Float16* buf, int tid,
                                              int rb, int items,
                                              h8 oreg[KMAX][2]) {
#pragma unroll
  for (int k = 0; k < KMAX; ++k) {
    int it = tid + k * NT;
    if (it < items) {
      int rp = it / G;                 // G is a compile-time constant
      int g = it - rp * G;
      int r0 = rb + 2 * rp;
      const _Float16* s0 = buf + (r0 - 1) * SW + 8 * (GLO + g);
      h8 a = *(const h8*)(s0);
      h8 b = *(const h8*)(s0 + SW);
      h8 c = *(const h8*)(s0 + 2 * SW);
      h8 d = *(const h8*)(s0 + 3 * SW);
      _Float16 le0 = hi_half(s0 + SW - 2);
      _Float16 le1 = hi_half(s0 + 2 * SW - 2);
      _Float16 re0 = lo_half(s0 + SW + 8);
      _Float16 re1 = lo_half(s0 + 2 * SW + 8);
      oreg[k][0] = __builtin_elementwise_min(
          min3v(a, b, c),
          __builtin_elementwise_min(shl1(b, le0), shr1(b, re0)));
      oreg[k][1] = __builtin_elementwise_min(
          min3v(b, c, d),
          __builtin_elementwise_min(shl1(c, le1), shr1(c, re1)));
    }
  }
}

template <int G, int GLO>
__device__ __forceinline__ void erode_write(_Float16* buf, int tid, int rb,
                                            int items, const h8 oreg[KMAX][2]) {
#pragma unroll
  for (int k = 0; k < KMAX; ++k) {
    int it = tid + k * NT;
    if (it < items) {
      int rp = it / G;
      int g = it - rp * G;
      int r0 = rb + 2 * rp;
      _Float16* d0 = buf + r0 * SW + 8 * (GLO + g);
      *(h8*)(d0) = oreg[k][0];
      *(h8*)(d0 + SW) = oreg[k][1];
    }
  }
}

__global__ __launch_bounds__(NT, 5) void cl_skel_kernel(
    const float* __restrict__ pred, const float* __restrict__ target,
    double* __restrict__ sums) {
  __shared__ _Float16 buf[SROWS * SW];
  __shared__ float rbuf[2][NT / 64];

  const int tid = threadIdx.x;
  const int tileIdx = blockIdx.x;
  const int batch = blockIdx.y;
  const bool isPred = (blockIdx.z == 0);
  const int tr = (tileIdx / TPD) * TILE;
  const int tc = (tileIdx % TPD) * TILE;
  const float* __restrict__ img = isPred ? pred : target;
  const float* __restrict__ other = isPred ? target : pred;
  const size_t base = (size_t)batch * (H * W);

  const bool border = (tr == 0) | (tc == 0) | (tr == H - TILE) | (tc == W - TILE);

  // ---- Stage x0 (fp16): rows 0..89, half cols 0..95 (24 float4 groups) ----
  if (!border) {
    for (int it = tid; it < SROWS * 24; it += NT) {
      int row = it / 24, g = it - row * 24;
      int gr = tr - 13 + row;
      int gc = tc - 16 + 4 * g;
      float4 v = ld4(&img[base + (size_t)gr * W + gc]);
      if (isPred) {
        v.x = sigmf(v.x); v.y = sigmf(v.y); v.z = sigmf(v.z); v.w = sigmf(v.w);
      }
      h4 hv;
      hv[0] = (_Float16)v.x; hv[1] = (_Float16)v.y;
      hv[2] = (_Float16)v.z; hv[3] = (_Float16)v.w;
      *(h4*)(buf + row * SW + 4 * g) = hv;
    }
  } else {
    for (int it = tid; it < SROWS * 24; it += NT) {
      int row = it / 24, g = it - row * 24;
      int gr = min(max(tr - 13 + row, 0), H - 1);
      int gc = tc - 16 + 4 * g;
      float4 v;
      v.x = img[base + (size_t)gr * W + min(max(gc + 0, 0), W - 1)];
      v.y = img[base + (size_t)gr * W + min(max(gc + 1, 0), W - 1)];
      v.z = img[base + (size_t)gr * W + min(max(gc + 2, 0), W - 1)];
      v.w = img[base + (size_t)gr * W + min(max(gc + 3, 0), W - 1)];
      if (isPred) {
        v.x = sigmf(v.x); v.y = sigmf(v.y); v.z = sigmf(v.z); v.w = sigmf(v.w);
      }
      h4 hv;
      hv[0] = (_Float16)v.x; hv[1] = (_Float16)v.y;
      hv[2] = (_Float16)v.z; hv[3] = (_Float16)v.w;
      *(h4*)(buf + row * SW + 4 * g) = hv;
    }
  }
  __syncthreads();

  const int ty = tid >> 2;  // 0..63: own tile row
  const int tg = tid & 3;   // 0..3 : own 16-col group
  const int rr = 13 + ty;
  const int c0 = 16 + 16 * tg;

  h8 skelE = (h8)(_Float16)0.0f;
  h8 skelF = (h8)(_Float16)0.0f;

#pragma unroll 1
  for (int R = 11; R >= 1; --R) {
    // ---- erode compute (in-register): rows [13-R,76+R] pairs ----
    const int rb = 13 - R;
    h8 oreg[KMAX][2];
    int items;
    if (R >= 9) {
      items = (32 + R) * 12;
      erode_compute<12, 0>(buf, tid, rb, items, oreg);
    } else {
      items = (32 + R) * 10;
      erode_compute<10, 1>(buf, tid, rb, items, oreg);
    }

    // t0 = x_{k-1} at own 16 px — must also be read before any write
    const _Float16* ps = buf + rr * SW + c0;
    h8 t0E = *(const h8*)ps;
    h8 t0F = *(const h8*)(ps + 8);

    __syncthreads();  // A: all reads of the old level complete

    // ---- write-back in place ----
    if (R >= 9) {
      erode_write<12, 0>(buf, tid, rb, items, oreg);
    } else {
      erode_write<10, 1>(buf, tid, rb, items, oreg);
    }
    __syncthreads();  // B: level-R now fully in buf

    // ---- dilate(buf) at own 16 px; skel update ----
    {
      const _Float16* pm = buf + (rr - 1) * SW + c0;
      h8 aE = *(const h8*)(pm),          aF = *(const h8*)(pm + 8);
      h8 bE = *(const h8*)(pm + SW),     bF = *(const h8*)(pm + SW + 8);
      h8 cE = *(const h8*)(pm + 2 * SW), cF = *(const h8*)(pm + 2 * SW + 8);
      _Float16 vl = hmax3(hi_half(pm - 2), hi_half(pm + SW - 2),
                          hi_half(pm + 2 * SW - 2));
      _Float16 vr = hmax3(lo_half(pm + 16), lo_half(pm + SW + 16),
                          lo_half(pm + 2 * SW + 16));
      h8 vmE = max3v(aE, bE, cE);
      h8 vmF = max3v(aF, bF, cF);
      h8 hE = max3v(shl1(vmE, vl), vmE, shr1(vmE, vmF[0]));
      h8 hF = max3v(shl1(vmF, vmE[7]), vmF, shr1(vmF, vr));
      h8 z = (h8)(_Float16)0.0f;
      h8 dE = __builtin_elementwise_max(t0E - hE, z);
      h8 dF = __builtin_elementwise_max(t0F - hF, z);
      skelE += __builtin_elementwise_max(dE - skelE * dE, z);
      skelF += __builtin_elementwise_max(dF - skelF * dF, z);
    }
    // next pass reads buf (level R) pre-its-barrier-A: reads only, safe.
  }

  // ---- Products with the other image over own 16 px ----
  const float* orow = other + base + (size_t)(tr + ty) * W + tc + 16 * tg;
  float s0 = 0.0f, s1 = 0.0f;
#pragma unroll
  for (int q = 0; q < 4; ++q) {
    float4 o = ld4(orow + 4 * q);
    if (!isPred) {
      o.x = sigmf(o.x); o.y = sigmf(o.y); o.z = sigmf(o.z); o.w = sigmf(o.w);
    }
    float sk0, sk1, sk2, sk3;
    if (q < 2) {
      sk0 = (float)skelE[4 * q + 0]; sk1 = (float)skelE[4 * q + 1];
      sk2 = (float)skelE[4 * q + 2]; sk3 = (float)skelE[4 * q + 3];
    } else {
      sk0 = (float)skelF[4 * q - 8]; sk1 = (float)skelF[4 * q - 7];
      sk2 = (float)skelF[4 * q - 6]; sk3 = (float)skelF[4 * q - 5];
    }
    s0 += (sk0 + sk1) + (sk2 + sk3);
    s1 += (sk0 * o.x + sk1 * o.y) + (sk2 * o.z + sk3 * o.w);
  }

#pragma unroll
  for (int off = 32; off > 0; off >>= 1) {
    s0 += __shfl_down(s0, off, 64);
    s1 += __shfl_down(s1, off, 64);
  }
  const int wave = tid >> 6;
  const int lane = tid & 63;
  if (lane == 0) {
    rbuf[0][wave] = s0;
    rbuf[1][wave] = s1;
  }
  __syncthreads();
  if (tid == 0) {
    float t0 = 0.0f, t1 = 0.0f;
#pragma unroll
    for (int w = 0; w < NT / 64; ++w) {
      t0 += rbuf[0][w];
      t1 += rbuf[1][w];
    }
    const int bank = (int)(blockIdx.x & (NBANKS - 1));
    const int o2 = (isPred ? 0 : 2);
    atomicAdd(&sums[bank * BANK_STRIDE + o2], (double)t0);
    atomicAdd(&sums[bank * BANK_STRIDE + o2 + 1], (double)t1);
  }
}

__global__ void cl_finalize_kernel(const double* __restrict__ sums,
                                   float* __restrict__ out) {
  double s[4] = {0.0, 0.0, 0.0, 0.0};
  for (int b = 0; b < NBANKS; ++b)
    for (int j = 0; j < 4; ++j) s[j] += sums[b * BANK_STRIDE + j];
  double tprec = (s[1] + 1.0) / (s[0] + 1.0);
  double tsens = (s[3] + 1.0) / (s[2] + 1.0);
  double cl = 2.0 * tprec * tsens / (tprec + tsens + 1e-7);
  out[0] = (float)(1.0 - cl);
}

extern "C" void kernel_launch(void* const* d_in, const int* in_sizes, int n_in,
                              void* d_out, int out_size, void* d_ws,
                              size_t ws_size, hipStream_t stream) {
  const float* pred = (const float*)d_in[0];
  const float* target = (const float*)d_in[1];
  double* sums = (double*)d_ws;
  const int batch = in_sizes[0] / (H * W);  // 32

  hipMemsetAsync(d_ws, 0, NBANKS * BANK_STRIDE * sizeof(double), stream);
  dim3 grid(TPD * TPD, batch, 2);
  cl_skel_kernel<<<grid, NT, 0, stream>>>(pred, target, sums);
  cl_finalize_kernel<<<1, 1, 0, stream>>>(sums, (float*)d_out);
}

// Round 7
// 207.303 us; speedup vs baseline: 1.4770x; 1.4770x over previous
//
#include <hip/hip_runtime.h>

#define H 512
#define W 512
#define TILE 64
#define NT 256
#define SW 104                // LDS row stride in halfs (52 dwords, 20 banks)
#define SROWS 90
#define TPD (W / TILE)        // 8 tiles per dim
#define NBANKS 16
#define BANK_STRIDE 16
// Tile px (y,x) lives at LDS (13+y, 16+x) in half precision. Staging
// clamp-replicates true image borders; replication self-propagates through
// the erode chain (region shrinks 1 row/pass, matching contamination), so
// NO guard refresh is needed.
//
// SINGLE-buffer in-place erode: per pass: compute all outputs into NAMED
// h8 registers (all LDS reads pre-barrier, incl. t0), barrier A, write back
// in place, barrier B, dilate reads the new level. Pass R reads rows
// [12-R,78+R] == exactly the rows written by pass R+1 -> in-place safe.
// ROUND-2 LESSON (rocprof): h8 oreg[3][2] passed by pointer + conditional
// init went to SCRATCH -> 580 MB/dispatch HBM writes, occupancy 49%,
// 237us. Named scalars in one inlined function spanning the barriers keep
// the values in VGPRs (SSA phis), zero scratch.
//
// COLUMN TRIM: pass R's output is only consumed on half-cols [16-R,79+R].
// Group range glo=(16-R)>>3, ghi=(79+R)>>3 -> 12 groups R>=9, 10 for R<=8.
// Validity induction: V(11)=[1,94] ... V(R<=8)=[16-R,79+R] exactly; stale
// cols advance 1/pass staying exactly 1 col outside the consumed range;
// final dilate reads cols [15,80]=V(1), rows [12,77]. G is a template
// constant so it/G stays a magic-multiply.
// items: min 330 (R=1) >= NT -> k=0 unconditional; >512 only at R=11 -> K2.

typedef _Float16 h8 __attribute__((ext_vector_type(8)));
typedef _Float16 h4 __attribute__((ext_vector_type(4)));

__device__ __forceinline__ float sigmf(float x) {
  return 1.0f / (1.0f + __expf(-x));
}
__device__ __forceinline__ float4 ld4(const float* p) { return *(const float4*)p; }

__device__ __forceinline__ h8 min3v(h8 a, h8 b, h8 c) {
  return __builtin_elementwise_min(__builtin_elementwise_min(a, b), c);
}
__device__ __forceinline__ h8 max3v(h8 a, h8 b, h8 c) {
  return __builtin_elementwise_max(__builtin_elementwise_max(a, b), c);
}
__device__ __forceinline__ h8 shl1(h8 v, _Float16 e) {
  h8 r = __builtin_shufflevector(v, v, 7, 0, 1, 2, 3, 4, 5, 6);
  r[0] = e;
  return r;
}
__device__ __forceinline__ h8 shr1(h8 v, _Float16 e) {
  h8 r = __builtin_shufflevector(v, v, 1, 2, 3, 4, 5, 6, 7, 0);
  r[7] = e;
  return r;
}
// b32 loads of half pairs (keeps ds_read2 mergeability), extract one half.
__device__ __forceinline__ _Float16 hi_half(const _Float16* p) {
  unsigned v = *(const unsigned*)p;
  unsigned short s = (unsigned short)(v >> 16);
  return __builtin_bit_cast(_Float16, s);
}
__device__ __forceinline__ _Float16 lo_half(const _Float16* p) {
  unsigned v = *(const unsigned*)p;
  return __builtin_bit_cast(_Float16, (unsigned short)v);
}
__device__ __forceinline__ _Float16 hmax3(_Float16 a, _Float16 b, _Float16 c) {
  _Float16 m = a > b ? a : b;
  return m > c ? m : c;
}

// Erode 3x1/1x3-min stencil for a row pair at (r0, group gg): outputs oA
// (row r0) and oB (row r0+1). Reads rows r0-1..r0+2.
#define ERODE_AT(r0, gg, oA, oB)                                          \
  {                                                                       \
    const _Float16* s0 = buf + ((r0)-1) * SW + 8 * (GLO + (gg));          \
    h8 a = *(const h8*)(s0);                                              \
    h8 b = *(const h8*)(s0 + SW);                                         \
    h8 c = *(const h8*)(s0 + 2 * SW);                                     \
    h8 d = *(const h8*)(s0 + 3 * SW);                                     \
    _Float16 le0 = hi_half(s0 + SW - 2);                                  \
    _Float16 le1 = hi_half(s0 + 2 * SW - 2);                              \
    _Float16 re0 = lo_half(s0 + SW + 8);                                  \
    _Float16 re1 = lo_half(s0 + 2 * SW + 8);                              \
    oA = __builtin_elementwise_min(                                       \
        min3v(a, b, c),                                                   \
        __builtin_elementwise_min(shl1(b, le0), shr1(b, re0)));           \
    oB = __builtin_elementwise_min(                                       \
        min3v(b, c, d),                                                   \
        __builtin_elementwise_min(shl1(c, le1), shr1(c, re1)));           \
  }

#define WRITE_AT(r0, gg, oA, oB)                             \
  {                                                          \
    _Float16* d0 = buf + (r0)*SW + 8 * (GLO + (gg));         \
    *(h8*)(d0) = oA;                                         \
    *(h8*)(d0 + SW) = oB;                                    \
  }

// One full in-place erode pass (compute -> barrier -> write -> barrier).
// All state in named registers spanning the barriers.
template <int G, int GLO, bool K2>
__device__ __forceinline__ void erode_pass(_Float16* buf, int tid, int rb,
                                           int items) {
  const int rp0 = tid / G;  // G compile-time: magic-multiply
  const int g0 = tid - rp0 * G;
  const int r00 = rb + 2 * rp0;

  const int it1 = tid + NT;
  const bool a1 = it1 < items;
  const int rp1 = it1 / G;
  const int g1 = it1 - rp1 * G;
  const int r01 = rb + 2 * rp1;

  const int it2 = tid + 2 * NT;
  const bool a2 = K2 && (it2 < items);
  const int rp2 = it2 / G;
  const int g2 = it2 - rp2 * G;
  const int r02 = rb + 2 * rp2;

  h8 o00, o01, o10, o11, o20, o21;
  ERODE_AT(r00, g0, o00, o01);            // k=0 always active (items>=330)
  if (a1) ERODE_AT(r01, g1, o10, o11);
  if (K2) {
    if (a2) ERODE_AT(r02, g2, o20, o21);
  }

  __syncthreads();  // A: all reads of the old level complete

  WRITE_AT(r00, g0, o00, o01);
  if (a1) WRITE_AT(r01, g1, o10, o11);
  if (K2) {
    if (a2) WRITE_AT(r02, g2, o20, o21);
  }

  __syncthreads();  // B: new level fully in buf
}

__global__ __launch_bounds__(NT, 5) void cl_skel_kernel(
    const float* __restrict__ pred, const float* __restrict__ target,
    double* __restrict__ sums) {
  __shared__ _Float16 buf[SROWS * SW];
  __shared__ float rbuf[2][NT / 64];

  const int tid = threadIdx.x;
  const int tileIdx = blockIdx.x;
  const int batch = blockIdx.y;
  const bool isPred = (blockIdx.z == 0);
  const int tr = (tileIdx / TPD) * TILE;
  const int tc = (tileIdx % TPD) * TILE;
  const float* __restrict__ img = isPred ? pred : target;
  const float* __restrict__ other = isPred ? target : pred;
  const size_t base = (size_t)batch * (H * W);

  const bool border = (tr == 0) | (tc == 0) | (tr == H - TILE) | (tc == W - TILE);

  // ---- Stage x0 (fp16): rows 0..89, half cols 0..95 (24 float4 groups) ----
  if (!border) {
    for (int it = tid; it < SROWS * 24; it += NT) {
      int row = it / 24, g = it - row * 24;
      int gr = tr - 13 + row;
      int gc = tc - 16 + 4 * g;
      float4 v = ld4(&img[base + (size_t)gr * W + gc]);
      if (isPred) {
        v.x = sigmf(v.x); v.y = sigmf(v.y); v.z = sigmf(v.z); v.w = sigmf(v.w);
      }
      h4 hv;
      hv[0] = (_Float16)v.x; hv[1] = (_Float16)v.y;
      hv[2] = (_Float16)v.z; hv[3] = (_Float16)v.w;
      *(h4*)(buf + row * SW + 4 * g) = hv;
    }
  } else {
    for (int it = tid; it < SROWS * 24; it += NT) {
      int row = it / 24, g = it - row * 24;
      int gr = min(max(tr - 13 + row, 0), H - 1);
      int gc = tc - 16 + 4 * g;
      float4 v;
      v.x = img[base + (size_t)gr * W + min(max(gc + 0, 0), W - 1)];
      v.y = img[base + (size_t)gr * W + min(max(gc + 1, 0), W - 1)];
      v.z = img[base + (size_t)gr * W + min(max(gc + 2, 0), W - 1)];
      v.w = img[base + (size_t)gr * W + min(max(gc + 3, 0), W - 1)];
      if (isPred) {
        v.x = sigmf(v.x); v.y = sigmf(v.y); v.z = sigmf(v.z); v.w = sigmf(v.w);
      }
      h4 hv;
      hv[0] = (_Float16)v.x; hv[1] = (_Float16)v.y;
      hv[2] = (_Float16)v.z; hv[3] = (_Float16)v.w;
      *(h4*)(buf + row * SW + 4 * g) = hv;
    }
  }
  __syncthreads();

  const int ty = tid >> 2;  // 0..63: own tile row
  const int tg = tid & 3;   // 0..3 : own 16-col group
  const int rr = 13 + ty;
  const int c0 = 16 + 16 * tg;

  h8 skelE = (h8)(_Float16)0.0f;
  h8 skelF = (h8)(_Float16)0.0f;

#pragma unroll 1
  for (int R = 11; R >= 1; --R) {
    const int rb = 13 - R;

    // t0 = x_{k-1} at own 16 px — read before any in-place write (pre-barrier A)
    const _Float16* ps = buf + rr * SW + c0;
    h8 t0E = *(const h8*)ps;
    h8 t0F = *(const h8*)(ps + 8);

    if (R == 11) {
      erode_pass<12, 0, true>(buf, tid, rb, 43 * 12);
    } else if (R >= 9) {
      erode_pass<12, 0, false>(buf, tid, rb, (32 + R) * 12);
    } else {
      erode_pass<10, 1, false>(buf, tid, rb, (32 + R) * 10);
    }

    // ---- dilate(buf) at own 16 px; skel update ----
    {
      const _Float16* pm = buf + (rr - 1) * SW + c0;
      h8 aE = *(const h8*)(pm),          aF = *(const h8*)(pm + 8);
      h8 bE = *(const h8*)(pm + SW),     bF = *(const h8*)(pm + SW + 8);
      h8 cE = *(const h8*)(pm + 2 * SW), cF = *(const h8*)(pm + 2 * SW + 8);
      _Float16 vl = hmax3(hi_half(pm - 2), hi_half(pm + SW - 2),
                          hi_half(pm + 2 * SW - 2));
      _Float16 vr = hmax3(lo_half(pm + 16), lo_half(pm + SW + 16),
                          lo_half(pm + 2 * SW + 16));
      h8 vmE = max3v(aE, bE, cE);
      h8 vmF = max3v(aF, bF, cF);
      h8 hE = max3v(shl1(vmE, vl), vmE, shr1(vmE, vmF[0]));
      h8 hF = max3v(shl1(vmF, vmE[7]), vmF, shr1(vmF, vr));
      h8 z = (h8)(_Float16)0.0f;
      h8 dE = __builtin_elementwise_max(t0E - hE, z);
      h8 dF = __builtin_elementwise_max(t0F - hF, z);
      skelE += __builtin_elementwise_max(dE - skelE * dE, z);
      skelF += __builtin_elementwise_max(dF - skelF * dF, z);
    }
    // next pass reads buf (level R) pre-its-barrier-A: reads only, safe.
  }

  // ---- Products with the other image over own 16 px ----
  const float* orow = other + base + (size_t)(tr + ty) * W + tc + 16 * tg;
  float s0 = 0.0f, s1 = 0.0f;
#pragma unroll
  for (int q = 0; q < 4; ++q) {
    float4 o = ld4(orow + 4 * q);
    if (!isPred) {
      o.x = sigmf(o.x); o.y = sigmf(o.y); o.z = sigmf(o.z); o.w = sigmf(o.w);
    }
    float sk0, sk1, sk2, sk3;
    if (q < 2) {
      sk0 = (float)skelE[4 * q + 0]; sk1 = (float)skelE[4 * q + 1];
      sk2 = (float)skelE[4 * q + 2]; sk3 = (float)skelE[4 * q + 3];
    } else {
      sk0 = (float)skelF[4 * q - 8]; sk1 = (float)skelF[4 * q - 7];
      sk2 = (float)skelF[4 * q - 6]; sk3 = (float)skelF[4 * q - 5];
    }
    s0 += (sk0 + sk1) + (sk2 + sk3);
    s1 += (sk0 * o.x + sk1 * o.y) + (sk2 * o.z + sk3 * o.w);
  }

#pragma unroll
  for (int off = 32; off > 0; off >>= 1) {
    s0 += __shfl_down(s0, off, 64);
    s1 += __shfl_down(s1, off, 64);
  }
  const int wave = tid >> 6;
  const int lane = tid & 63;
  if (lane == 0) {
    rbuf[0][wave] = s0;
    rbuf[1][wave] = s1;
  }
  __syncthreads();
  if (tid == 0) {
    float t0 = 0.0f, t1 = 0.0f;
#pragma unroll
    for (int w = 0; w < NT / 64; ++w) {
      t0 += rbuf[0][w];
      t1 += rbuf[1][w];
    }
    const int bank = (int)(blockIdx.x & (NBANKS - 1));
    const int o2 = (isPred ? 0 : 2);
    atomicAdd(&sums[bank * BANK_STRIDE + o2], (double)t0);
    atomicAdd(&sums[bank * BANK_STRIDE + o2 + 1], (double)t1);
  }
}

__global__ void cl_finalize_kernel(const double* __restrict__ sums,
                                   float* __restrict__ out) {
  double s[4] = {0.0, 0.0, 0.0, 0.0};
  for (int b = 0; b < NBANKS; ++b)
    for (int j = 0; j < 4; ++j) s[j] += sums[b * BANK_STRIDE + j];
  double tprec = (s[1] + 1.0) / (s[0] + 1.0);
  double tsens = (s[3] + 1.0) / (s[2] + 1.0);
  double cl = 2.0 * tprec * tsens / (tprec + tsens + 1e-7);
  out[0] = (float)(1.0 - cl);
}

extern "C" void kernel_launch(void* const* d_in, const int* in_sizes, int n_in,
                              void* d_out, int out_size, void* d_ws,
                              size_t ws_size, hipStream_t stream) {
  const float* pred = (const float*)d_in[0];
  const float* target = (const float*)d_in[1];
  double* sums = (double*)d_ws;
  const int batch = in_sizes[0] / (H * W);  // 32

  hipMemsetAsync(d_ws, 0, NBANKS * BANK_STRIDE * sizeof(double), stream);
  dim3 grid(TPD * TPD, batch, 2);
  cl_skel_kernel<<<grid, NT, 0, stream>>>(pred, target, sums);
  cl_finalize_kernel<<<1, 1, 0, stream>>>(sums, (float*)d_out);
}